// Round 5
// baseline (434.951 us; speedup 1.0000x reference)
//
#include <hip/hip_runtime.h>

// FrameLogLikelihood segment-mean:
//   input  [B_SEQ*K, M] f32, B_SEQ=2048, K=2001, M=16
//   output [B_SEQ, 6*M] f32
//
// R8 DIAGNOSTIC (sacrificial round): rep 0 is bit-identical to the R5
// kernel (contiguous nt streaming + LDS reduction). Reps 1..3 re-read the
// whole input via asm-volatile nt loads with results discarded, purely to
// inflate this dispatch past the ~157 us fillBufferAligned rows so rocprof
// finally reports the kernel's OWN dur / FETCH_SIZE / WRITE_SIZE:
//   - WRITE_SIZE ~256 MB  -> nt loads allocate & force dirty-ws writebacks
//   - FETCH ~1 GB, reps equal-speed -> policy-independent stream limit
//   - dur ~180-250 us total -> kernel was already fast; floor is harness
// Each asm block has s_waitcnt vmcnt(0) INSIDE (no outstanding-load or
// early-clobber hazards; this is the crash-safe single-load form).

constexpr int K    = 2001;
constexpr int M    = 16;
constexpr int NSEQ = 2048;
constexpr int NV   = K * 4;   // 8004 float4 per sequence
constexpr int NT   = 384;     // 6 waves; stride of 96 rows keeps j%3 fixed

typedef float v4f __attribute__((ext_vector_type(4)));

__global__ __launch_bounds__(NT) void
seg_mean_kernel(const float* __restrict__ in, float* __restrict__ out) {
    const int b = blockIdx.x;
    const int t = threadIdx.x;

    const v4f* __restrict__ base =
        reinterpret_cast<const v4f*>(in + (size_t)b * K * M);

    v4f accL = (v4f)(0.0f);   // rows 0..999,  group (t>>2)%3
    v4f accR = (v4f)(0.0f);   // rows 1001..2000, group 3+((t>>2)%3+1)%3

    // --- rep 0: the real accumulation (identical to the verified R5 pass)
    for (int i = t; i < NV; i += NT) {
        v4f v = __builtin_nontemporal_load(&base[i]);
        const int j = i >> 2;
        if (j < 1000) {
            accL += v;
        } else if (j > 1000) {
            accR += v;
        }
        // j == 1000: overlap row, dropped.
    }

    // --- reps 1..3: dummy full re-reads, same nt policy, results discarded.
    // asm volatile: not CSE-able against rep 0, not DCE-able. vmcnt(0)
    // inside each block -> zero outstanding-load hazard at wave end.
    for (int rep = 1; rep < 4; ++rep) {
        for (int i = t; i < NV; i += NT) {
            const v4f* p = base + i;
            v4f v;
            asm volatile(
                "global_load_dwordx4 %0, %1, off nt\n\t"
                "s_waitcnt vmcnt(0)"
                : "=v"(v)
                : "v"(p));
            (void)v;
        }
    }

    // Reduction: threads with equal key = t%12 share (residue c = key>>2,
    // quad q = key&3); rank m = t/12 in 0..31.
    __shared__ v4f lds[2][12][33];
    const int key = t % 12;
    const int m   = t / 12;
    lds[0][key][m] = accL;
    lds[1][key][m] = accR;
    __syncthreads();

    if (t < 24) {
        const int region = t / 12;      // 0 = left, 1 = right
        const int k2     = t % 12;
        const int c      = k2 >> 2;
        const int q      = k2 & 3;

        v4f s = (v4f)(0.0f);
#pragma unroll
        for (int mm = 0; mm < 32; ++mm) {
            s += lds[region][k2][(mm + k2) & 31];  // staggered start
        }

        const int g = (region == 0) ? c : 3 + ((c + 1) % 3);
        // counts: g0/g3 -> 334 rows, others 333
        const float cnt = (g == 0 || g == 3) ? 334.0f : 333.0f;
        v4f r = s * (1.0f / cnt);

        v4f* o = reinterpret_cast<v4f*>(out + (size_t)b * 96 + g * 16 + q * 4);
        __builtin_nontemporal_store(r, o);
    }
}

extern "C" void kernel_launch(void* const* d_in, const int* in_sizes, int n_in,
                              void* d_out, int out_size, void* d_ws, size_t ws_size,
                              hipStream_t stream) {
    const float* in = (const float*)d_in[0];
    float* out = (float*)d_out;
    seg_mean_kernel<<<NSEQ, NT, 0, stream>>>(in, out);
}

// Round 6
// 322.158 us; speedup vs baseline: 1.3501x; 1.3501x over previous
//
#include <hip/hip_runtime.h>

// FrameLogLikelihood segment-mean:
//   input  [B_SEQ*K, M] f32, B_SEQ=2048, K=2001, M=16
//   output [B_SEQ, 6*M] f32
//
// Decomposition established by the R8 diagnostic (kernel's own counters):
//   dur_us = fill(157, harness) + overhead(115, harness) + kernel
//   R5 kernel phase ~51 us = 262 MB cold read at 5.2 TB/s (82% of 6.3).
//   WRITE_SIZE = 768 KB (output only) -> no forced writebacks; the ws-fill
//   fully drains to HBM in its own dispatch. nt loads remain the right
//   policy (cacheable was +28 us, R6).
//
// R9: revert diagnostic reps; push MLP. R5's loop had trip count 21/20
// (t<324 vs t>=324) -> compiler can't fully unroll -> shallow VMEM queue.
// Split into a constant-trip 20-iteration fully-unrolled loop + tail.
// Tail (i = t + 7680, t < 324): j = i>>2 in [1920,2000], all > 1000 ->
// unconditional accR. Per-thread accumulation order unchanged -> result
// bit-identical to R5.

constexpr int K    = 2001;
constexpr int M    = 16;
constexpr int NSEQ = 2048;
constexpr int NV   = K * 4;   // 8004 float4 per sequence
constexpr int NT   = 384;     // 6 waves; 96 rows/step keeps j%3 fixed

typedef float v4f __attribute__((ext_vector_type(4)));

__global__ __launch_bounds__(NT) void
seg_mean_kernel(const float* __restrict__ in, float* __restrict__ out) {
    const int b = blockIdx.x;
    const int t = threadIdx.x;

    const v4f* __restrict__ base =
        reinterpret_cast<const v4f*>(in + (size_t)b * K * M);

    v4f accL = (v4f)(0.0f);   // rows 0..999,  group (t>>2)%3
    v4f accR = (v4f)(0.0f);   // rows 1001..2000, group 3+((t>>2)%3+1)%3

    // Constant-trip main loop: i = t + 384*m, m = 0..19 (max i = 7679).
    // Full unroll lets the compiler hoist nt loads and keep a deep VMEM
    // queue per wave (the 5.2 -> 6.3 TB/s lever).
#pragma unroll
    for (int m = 0; m < 20; ++m) {
        const int i = t + m * NT;
        v4f v = __builtin_nontemporal_load(&base[i]);
        const int j = i >> 2;
        if (j < 1000) {
            accL += v;
        } else if (j > 1000) {
            accR += v;
        }
        // j == 1000: overlap row, dropped.
    }

    // Tail: i = t + 7680 < 8004 only for t < 324; those rows are all
    // right-region (j in [1920,2000] > 1000).
    {
        const int i = t + 20 * NT;
        if (i < NV) {
            accR += __builtin_nontemporal_load(&base[i]);
        }
    }

    // Reduction: threads with equal key = t%12 share (residue c = key>>2,
    // quad q = key&3); rank m = t/12 in 0..31.  33-slot rows kill the
    // 512B-stride bank aliasing in the second phase.
    __shared__ v4f lds[2][12][33];
    const int key = t % 12;
    const int m   = t / 12;
    lds[0][key][m] = accL;
    lds[1][key][m] = accR;
    __syncthreads();

    if (t < 24) {
        const int region = t / 12;      // 0 = left, 1 = right
        const int k2     = t % 12;
        const int c      = k2 >> 2;
        const int q      = k2 & 3;

        v4f s = (v4f)(0.0f);
#pragma unroll
        for (int mm = 0; mm < 32; ++mm) {
            s += lds[region][k2][(mm + k2) & 31];  // staggered start
        }

        const int g = (region == 0) ? c : 3 + ((c + 1) % 3);
        // counts: g0/g3 -> 334 rows, others 333
        const float cnt = (g == 0 || g == 3) ? 334.0f : 333.0f;
        v4f r = s * (1.0f / cnt);

        v4f* o = reinterpret_cast<v4f*>(out + (size_t)b * 96 + g * 16 + q * 4);
        __builtin_nontemporal_store(r, o);
    }
}

extern "C" void kernel_launch(void* const* d_in, const int* in_sizes, int n_in,
                              void* d_out, int out_size, void* d_ws, size_t ws_size,
                              hipStream_t stream) {
    const float* in = (const float*)d_in[0];
    float* out = (float*)d_out;
    seg_mean_kernel<<<NSEQ, NT, 0, stream>>>(in, out);
}